// Round 10
// baseline (144.194 us; speedup 1.0000x reference)
//
#include <hip/hip_runtime.h>
#include <hip/hip_bf16.h>

typedef __bf16 bf16x8 __attribute__((ext_vector_type(8)));
typedef float  f32x4  __attribute__((ext_vector_type(4)));
typedef unsigned short u16;

static constexpr int N = 8192;
static constexpr int D = 32;
static constexpr float L2E = 1.44269504088896340736f;
static constexpr float MSHIFT = 32.0f;  // fixed softmax shift (log2 domain)

// forced global load, 16B; volatile asm = scheduling region boundary, cannot
// be sunk/serialized by the compiler. Arrival enforced by explicit s_waitcnt.
__device__ __forceinline__ bf16x8 ld16(const u16* p) {
  int4 r;
  asm volatile("global_load_dwordx4 %0, %1, off" : "=v"(r) : "v"(p));
  return __builtin_bit_cast(bf16x8, r);
}
__device__ __forceinline__ void waitvm(int n) {
  if (n == 8)
    asm volatile("s_waitcnt vmcnt(8)" ::: "memory");
  else
    asm volatile("s_waitcnt vmcnt(0)" ::: "memory");
  __builtin_amdgcn_sched_barrier(0);  // rule #18: block MFMA hoisting past wait
}

// ---------------- prep ----------------
// blocks 0..255: Q*log2e -> bf16, K -> bf16 row-major.
// blocks 256..383: V -> bf16 Vt2[d][col]: within each 64-key block, columns
// permuted to PV-fragment order: phys col u*32+g*8+j holds logical key
// u*32 + 4g + (j&3) + 16*(j>>2)  -> flash reads one dwordx4 per fragment.
// block 0 zeroes the 64 q-group arrival counters.
__global__ __launch_bounds__(256) void prep_kernel(
    const float* __restrict__ Q, const float* __restrict__ K,
    const float* __restrict__ V, u16* __restrict__ Qb, u16* __restrict__ Kb,
    u16* __restrict__ Vt, int* __restrict__ cnt) {
  __shared__ float tile[64][33];
  const int b = blockIdx.x;
  if (b == 0 && threadIdx.x < 64) cnt[threadIdx.x] = 0;
  auto pack = [](float x, float y) -> unsigned int {
    u16 ux = __builtin_bit_cast(u16, (__bf16)x);
    u16 uy = __builtin_bit_cast(u16, (__bf16)y);
    return (unsigned int)ux | ((unsigned int)uy << 16);
  };
  if (b < 256) {
    const int i = (b * 256 + threadIdx.x) * 4;
    const float4 q = *reinterpret_cast<const float4*>(Q + i);
    const float4 k = *reinterpret_cast<const float4*>(K + i);
    uint2 qo = { pack(q.x * L2E, q.y * L2E), pack(q.z * L2E, q.w * L2E) };
    uint2 ko = { pack(k.x, k.y), pack(k.z, k.w) };
    *reinterpret_cast<uint2*>(Qb + i) = qo;
    *reinterpret_cast<uint2*>(Kb + i) = ko;
  } else {
    const int r0 = (b - 256) * 64;
    const int row = threadIdx.x >> 2;        // key 0..63
    const int c0 = (threadIdx.x & 3) * 8;    // d 0,8,16,24
    const float4 x0 = *reinterpret_cast<const float4*>(V + (size_t)(r0 + row) * D + c0);
    const float4 x1 = *reinterpret_cast<const float4*>(V + (size_t)(r0 + row) * D + c0 + 4);
    tile[row][c0 + 0] = x0.x; tile[row][c0 + 1] = x0.y;
    tile[row][c0 + 2] = x0.z; tile[row][c0 + 3] = x0.w;
    tile[row][c0 + 4] = x1.x; tile[row][c0 + 5] = x1.y;
    tile[row][c0 + 6] = x1.z; tile[row][c0 + 7] = x1.w;
    __syncthreads();
    const int d = threadIdx.x >> 3;          // 0..31
    const int u = (threadIdx.x >> 2) & 1;    // 32-key unit
    const int g = threadIdx.x & 3;
    const int u32b = u * 32 + 4 * g;
    uint4 o;
    o.x = pack(tile[u32b + 0][d],  tile[u32b + 1][d]);
    o.y = pack(tile[u32b + 2][d],  tile[u32b + 3][d]);
    o.z = pack(tile[u32b + 16][d], tile[u32b + 17][d]);
    o.w = pack(tile[u32b + 18][d], tile[u32b + 19][d]);
    *reinterpret_cast<uint4*>(Vt + (size_t)d * N + r0 + u * 32 + g * 8) = o;
  }
}

// ---------------- main flash kernel: no LDS, counted-vmcnt register pipeline ----------------
// 256 threads = 4 independent waves; wave owns 32 q-rows, streams KPB keys in
// 64-key tiles directly from global (L2-hot; bid=qg*NS+sp clusters each split
// on one XCD's L2). Per tile: 8 forced 16B loads (4 K + 4 V), issued one full
// tile ahead; s_waitcnt vmcnt(8) at tile top waits only for the CURRENT
// tile's loads (next tile stays in flight -> never drains to 0 mid-loop).
// Softmax: fixed max (C=-32, log2 domain, Q pre-scaled by log2e) — exact.
template <int NS>
__global__ __launch_bounds__(256, 3) void flash_kernel(
    const u16* __restrict__ Qb, const u16* __restrict__ Kb,
    const u16* __restrict__ Vt, float* __restrict__ lP,
    float* __restrict__ OP, float* __restrict__ out, int* __restrict__ cnt) {
  constexpr int KPB = N / NS;
  constexpr int NT = KPB / 64;
  __shared__ int last_flag;

  const int tid = threadIdx.x;
  const int lane = tid & 63;
  const int w = tid >> 6;
  const int a = lane & 15;
  const int g = lane >> 4;
  const int qg = blockIdx.x / NS;
  const int sp = blockIdx.x % NS;
  const int qr0 = qg * 128 + w * 32;
  const int k0 = sp * KPB;

  const bf16x8 qfA = *reinterpret_cast<const bf16x8*>(Qb + (qr0 + a) * D + g * 8);
  const bf16x8 qfB = *reinterpret_cast<const bf16x8*>(Qb + (qr0 + 16 + a) * D + g * 8);

  const u16* __restrict__ kbase = Kb + (size_t)(k0 + a) * D + g * 8;  // +t4*512, tile*2048
  const u16* __restrict__ vb0 = Vt + (size_t)a * N + k0 + g * 8;       // +u*32, tile*64
  const u16* __restrict__ vb1 = Vt + (size_t)(16 + a) * N + k0 + g * 8;

  const f32x4 minit = {-MSHIFT, -MSHIFT, -MSHIFT, -MSHIFT};
  const f32x4 zero4 = {0.f, 0.f, 0.f, 0.f};
  f32x4 accA0 = zero4, accA1 = zero4, accB0 = zero4, accB1 = zero4;
  float lA = 0.f, lB = 0.f;

  bf16x8 kA0, kA1, kA2, kA3, vA0, vA1, vA2, vA3;  // even tiles
  bf16x8 kB0, kB1, kB2, kB3, vB0, vB1, vB2, vB3;  // odd tiles

#define ISSUE(S, T)                                   \
  do {                                                \
    const u16* kp = kbase + (size_t)(T) * 2048;       \
    const u16* v0p = vb0 + (size_t)(T) * 64;          \
    const u16* v1p = vb1 + (size_t)(T) * 64;          \
    k##S##0 = ld16(kp);                               \
    k##S##1 = ld16(kp + 512);                         \
    k##S##2 = ld16(kp + 1024);                        \
    k##S##3 = ld16(kp + 1536);                        \
    v##S##0 = ld16(v0p);                              \
    v##S##1 = ld16(v0p + 32);                         \
    v##S##2 = ld16(v1p);                              \
    v##S##3 = ld16(v1p + 32);                         \
  } while (0)

#define COMPUTE(S)                                                             \
  do {                                                                         \
    f32x4 sA0 = __builtin_amdgcn_mfma_f32_16x16x32_bf16(k##S##0, qfA, minit, 0, 0, 0); \
    f32x4 sA1 = __builtin_amdgcn_mfma_f32_16x16x32_bf16(k##S##1, qfA, minit, 0, 0, 0); \
    f32x4 sA2 = __builtin_amdgcn_mfma_f32_16x16x32_bf16(k##S##2, qfA, minit, 0, 0, 0); \
    f32x4 sA3 = __builtin_amdgcn_mfma_f32_16x16x32_bf16(k##S##3, qfA, minit, 0, 0, 0); \
    f32x4 sB0 = __builtin_amdgcn_mfma_f32_16x16x32_bf16(k##S##0, qfB, minit, 0, 0, 0); \
    f32x4 sB1 = __builtin_amdgcn_mfma_f32_16x16x32_bf16(k##S##1, qfB, minit, 0, 0, 0); \
    f32x4 sB2 = __builtin_amdgcn_mfma_f32_16x16x32_bf16(k##S##2, qfB, minit, 0, 0, 0); \
    f32x4 sB3 = __builtin_amdgcn_mfma_f32_16x16x32_bf16(k##S##3, qfB, minit, 0, 0, 0); \
    float pA[16], pB[16];                                                      \
    _Pragma("unroll") for (int r = 0; r < 4; ++r) {                            \
      pA[r] = __builtin_amdgcn_exp2f(sA0[r]);                                  \
      pA[4 + r] = __builtin_amdgcn_exp2f(sA1[r]);                              \
      pA[8 + r] = __builtin_amdgcn_exp2f(sA2[r]);                              \
      pA[12 + r] = __builtin_amdgcn_exp2f(sA3[r]);                             \
      pB[r] = __builtin_amdgcn_exp2f(sB0[r]);                                  \
      pB[4 + r] = __builtin_amdgcn_exp2f(sB1[r]);                              \
      pB[8 + r] = __builtin_amdgcn_exp2f(sB2[r]);                              \
      pB[12 + r] = __builtin_amdgcn_exp2f(sB3[r]);                             \
    }                                                                          \
    float psA = 0.f, psB = 0.f;                                                \
    _Pragma("unroll") for (int r = 0; r < 16; ++r) {                           \
      psA += pA[r];                                                            \
      psB += pB[r];                                                            \
    }                                                                          \
    lA += psA;                                                                 \
    lB += psB;                                                                 \
    const bf16x8 pfA0 = {(__bf16)pA[0], (__bf16)pA[1], (__bf16)pA[2], (__bf16)pA[3],   \
                         (__bf16)pA[4], (__bf16)pA[5], (__bf16)pA[6], (__bf16)pA[7]};  \
    const bf16x8 pfA1 = {(__bf16)pA[8], (__bf16)pA[9], (__bf16)pA[10], (__bf16)pA[11], \
                         (__bf16)pA[12], (__bf16)pA[13], (__bf16)pA[14], (__bf16)pA[15]};\
    const bf16x8 pfB0 = {(__bf16)pB[0], (__bf16)pB[1], (__bf16)pB[2], (__bf16)pB[3],   \
                         (__bf16)pB[4], (__bf16)pB[5], (__bf16)pB[6], (__bf16)pB[7]};  \
    const bf16x8 pfB1 = {(__bf16)pB[8], (__bf16)pB[9], (__bf16)pB[10], (__bf16)pB[11], \
                         (__bf16)pB[12], (__bf16)pB[13], (__bf16)pB[14], (__bf16)pB[15]};\
    accA0 = __builtin_amdgcn_mfma_f32_16x16x32_bf16(v##S##0, pfA0, accA0, 0, 0, 0); \
    accA0 = __builtin_amdgcn_mfma_f32_16x16x32_bf16(v##S##1, pfA1, accA0, 0, 0, 0); \
    accA1 = __builtin_amdgcn_mfma_f32_16x16x32_bf16(v##S##2, pfA0, accA1, 0, 0, 0); \
    accA1 = __builtin_amdgcn_mfma_f32_16x16x32_bf16(v##S##3, pfA1, accA1, 0, 0, 0); \
    accB0 = __builtin_amdgcn_mfma_f32_16x16x32_bf16(v##S##0, pfB0, accB0, 0, 0, 0); \
    accB0 = __builtin_amdgcn_mfma_f32_16x16x32_bf16(v##S##1, pfB1, accB0, 0, 0, 0); \
    accB1 = __builtin_amdgcn_mfma_f32_16x16x32_bf16(v##S##2, pfB0, accB1, 0, 0, 0); \
    accB1 = __builtin_amdgcn_mfma_f32_16x16x32_bf16(v##S##3, pfB1, accB1, 0, 0, 0); \
  } while (0)

  ISSUE(A, 0);
  ISSUE(B, 1);
#pragma unroll
  for (int t = 0; t < NT; ++t) {
    waitvm(t == NT - 1 ? 0 : 8);
    if (t & 1) {
      COMPUTE(B);
      if (t + 2 < NT) ISSUE(B, t + 2);
    } else {
      COMPUTE(A);
      if (t + 2 < NT) ISSUE(A, t + 2);
    }
  }
#undef ISSUE
#undef COMPUTE

  // ---- epilogue: reduce l, store partials ----
  lA += __shfl_xor(lA, 16, 64);
  lA += __shfl_xor(lA, 32, 64);
  lB += __shfl_xor(lB, 16, 64);
  lB += __shfl_xor(lB, 32, 64);

  float* obA = OP + (size_t)(sp * N + qr0 + a) * D;
  float* obB = OP + (size_t)(sp * N + qr0 + 16 + a) * D;
  *reinterpret_cast<f32x4*>(obA + 4 * g) = accA0;
  *reinterpret_cast<f32x4*>(obA + 16 + 4 * g) = accA1;
  *reinterpret_cast<f32x4*>(obB + 4 * g) = accB0;
  *reinterpret_cast<f32x4*>(obB + 16 + 4 * g) = accB1;
  if (g == 0) {
    lP[sp * N + qr0 + a] = lA;
    lP[sp * N + qr0 + 16 + a] = lB;
  }

  // ---- fused combine: last split-block for this q-group does it ----
  __syncthreads();
  if (tid == 0) {
    __threadfence();
    const int v = __hip_atomic_fetch_add(&cnt[qg], 1, __ATOMIC_ACQ_REL,
                                         __HIP_MEMORY_SCOPE_AGENT);
    last_flag = (v == NS - 1);
  }
  __syncthreads();
  if (last_flag) {
    __threadfence();
#pragma unroll
    for (int k = 0; k < 4; ++k) {
      const int i4 = k * 256 + tid;
      const int q = qg * 128 + (i4 >> 3);
      const int db = i4 & 7;
      float L = 0.f;
      f32x4 o = {0.f, 0.f, 0.f, 0.f};
#pragma unroll
      for (int s = 0; s < NS; ++s) {
        L += lP[s * N + q];
        o += *reinterpret_cast<const f32x4*>(OP + ((size_t)s * N + q) * D + db * 4);
      }
      const float inv = 1.0f / L;
      *reinterpret_cast<f32x4*>(out + (size_t)q * D + db * 4) = o * inv;
    }
  }
}

extern "C" void kernel_launch(void* const* d_in, const int* in_sizes, int n_in,
                              void* d_out, int out_size, void* d_ws, size_t ws_size,
                              hipStream_t stream) {
  const float* Q = (const float*)d_in[0];
  const float* K = (const float*)d_in[1];
  const float* V = (const float*)d_in[2];
  float* out = (float*)d_out;

  const size_t base = (size_t)3 * N * D * sizeof(u16);
  const size_t per_split = (size_t)N * sizeof(float) + (size_t)N * D * sizeof(float);
  int ns = 16;
  while (ns > 4 && base + (size_t)ns * per_split + 256 > ws_size) ns >>= 1;

  u16* Qb = (u16*)d_ws;
  u16* Kb = Qb + N * D;
  u16* Vt = Kb + N * D;  // [D][N], PV-fragment-permuted columns
  float* lP = (float*)(Vt + N * D);
  float* OP = lP + ns * N;
  int* cnt = (int*)(OP + (size_t)ns * N * D);

  prep_kernel<<<256 + N / 64, 256, 0, stream>>>(Q, K, V, Qb, Kb, Vt, cnt);
  if (ns == 16)
    flash_kernel<16><<<64 * 16, 256, 0, stream>>>(Qb, Kb, Vt, lP, OP, out, cnt);
  else if (ns == 8)
    flash_kernel<8><<<64 * 8, 256, 0, stream>>>(Qb, Kb, Vt, lP, OP, out, cnt);
  else
    flash_kernel<4><<<64 * 4, 256, 0, stream>>>(Qb, Kb, Vt, lP, OP, out, cnt);
}

// Round 11
// 81.915 us; speedup vs baseline: 1.7603x; 1.7603x over previous
//
#include <hip/hip_runtime.h>
#include <hip/hip_bf16.h>

typedef __bf16 bf16x8 __attribute__((ext_vector_type(8)));
typedef __bf16 bf16x4 __attribute__((ext_vector_type(4)));
typedef float  f32x4  __attribute__((ext_vector_type(4)));
typedef unsigned short u16;

static constexpr int N = 8192;
static constexpr int D = 32;
static constexpr float L2E = 1.44269504088896340736f;
static constexpr float MSHIFT = 32.0f;  // fixed softmax shift (log2 domain)

// async global->LDS, 16B per lane; LDS dest = wave-uniform base + lane*16
__device__ __forceinline__ void gl_lds16(const u16* g, u16* l) {
  __builtin_amdgcn_global_load_lds(
      (const __attribute__((address_space(1))) unsigned int*)g,
      (__attribute__((address_space(3))) unsigned int*)l, 16, 0, 0);
}

// ---------------- prep ----------------
// blocks 0..255: Q*log2e -> bf16, K -> bf16 (row-major), vectorized.
// blocks 256..383: V -> bf16 V^T[d][k] via LDS fp32 tile (coalesced).
__global__ __launch_bounds__(256) void prep_kernel(
    const float* __restrict__ Q, const float* __restrict__ K,
    const float* __restrict__ V, u16* __restrict__ Qb, u16* __restrict__ Kb,
    u16* __restrict__ Vt) {
  __shared__ float tile[64][33];
  const int b = blockIdx.x;
  auto pack = [](float x, float y) -> unsigned int {
    u16 ux = __builtin_bit_cast(u16, (__bf16)x);
    u16 uy = __builtin_bit_cast(u16, (__bf16)y);
    return (unsigned int)ux | ((unsigned int)uy << 16);
  };
  if (b < 256) {
    const int i = (b * 256 + threadIdx.x) * 4;
    const float4 q = *reinterpret_cast<const float4*>(Q + i);
    const float4 k = *reinterpret_cast<const float4*>(K + i);
    uint2 qo = { pack(q.x * L2E, q.y * L2E), pack(q.z * L2E, q.w * L2E) };
    uint2 ko = { pack(k.x, k.y), pack(k.z, k.w) };
    *reinterpret_cast<uint2*>(Qb + i) = qo;
    *reinterpret_cast<uint2*>(Kb + i) = ko;
  } else {
    const int r0 = (b - 256) * 64;
    const int row = threadIdx.x >> 2;        // 0..63
    const int c0 = (threadIdx.x & 3) * 8;    // 0,8,16,24
    const float4 x0 = *reinterpret_cast<const float4*>(V + (size_t)(r0 + row) * D + c0);
    const float4 x1 = *reinterpret_cast<const float4*>(V + (size_t)(r0 + row) * D + c0 + 4);
    tile[row][c0 + 0] = x0.x; tile[row][c0 + 1] = x0.y;
    tile[row][c0 + 2] = x0.z; tile[row][c0 + 3] = x0.w;
    tile[row][c0 + 4] = x1.x; tile[row][c0 + 5] = x1.y;
    tile[row][c0 + 6] = x1.z; tile[row][c0 + 7] = x1.w;
    __syncthreads();
    const int d = threadIdx.x >> 3;          // 0..31
    const int kc = (threadIdx.x & 7) * 8;    // 0..56
    uint4 o;
    o.x = pack(tile[kc + 0][d], tile[kc + 1][d]);
    o.y = pack(tile[kc + 2][d], tile[kc + 3][d]);
    o.z = pack(tile[kc + 4][d], tile[kc + 5][d]);
    o.w = pack(tile[kc + 6][d], tile[kc + 7][d]);
    *reinterpret_cast<uint4*>(Vt + (size_t)d * N + r0 + kc) = o;
  }
}

// ---------------- main flash kernel ----------------
// r7 structure, but each wave owns 64 q-rows (4 Q-fragments): halves total
// waves, DMA bytes, LDS reads, and barriers per (q,key). 256 threads = 4
// waves; block owns 256 q-rows; KPB keys in 64-key tiles double-buffered in
// LDS via global_load_lds (16B/lane, linear dest). Swizzle on global source:
//   K: 16B slot p of key-row r holds logical slot p ^ ((r>>1)&3)
//   V: 16B block p of d-row holds logical block p ^ (d&7)
// Reads apply the same involution -> conflict-free.
// Softmax: fixed max (C=-32, log2 domain, Q pre-scaled by log2e), exact.
template <int NS>
__global__ __launch_bounds__(256, 2) void flash_kernel(
    const u16* __restrict__ Qb, const u16* __restrict__ Kb,
    const u16* __restrict__ Vt, float* __restrict__ lP,
    float* __restrict__ OP) {
  constexpr int KPB = N / NS;
  constexpr int NT = KPB / 64;
  __shared__ u16 Ks[2][2048];  // [buf][64 key * 32 u16]
  __shared__ u16 Vs[2][2048];  // [buf][32 d * 64 u16]

  const int tid = threadIdx.x;
  const int lane = tid & 63;
  const int wave = tid >> 6;  // 0..3
  const int a = lane & 15;
  const int g = lane >> 4;
  const int qg = blockIdx.x & 31;   // 32 q-groups of 256 rows
  const int sp = blockIdx.x >> 5;   // split
  const int qr0 = qg * 256 + wave * 64;
  const int k0 = sp * KPB;

  bf16x8 qf[4];
#pragma unroll
  for (int i = 0; i < 4; ++i)
    qf[i] = *reinterpret_cast<const bf16x8*>(Qb + (qr0 + 16 * i + a) * D + g * 8);

  // staging sources (pre-swizzled); LDS dest linear (wave base + lane*16B)
  const int krow = tid >> 2;                        // 0..63
  const int kslot = (tid & 3) ^ ((krow >> 1) & 3);  // phys slot for this src
  const u16* __restrict__ ksrc = Kb + krow * D + kslot * 8;
  const int vd = tid >> 3;                          // 0..31
  const int vlb = (tid & 7) ^ (vd & 7);             // logical 16B block
  const u16* __restrict__ vsrc = Vt + (size_t)vd * N + vlb * 8;
  u16* const kdst = &Ks[0][0] + wave * 512;
  u16* const vdst = &Vs[0][0] + wave * 512;

  const f32x4 minit = {-MSHIFT, -MSHIFT, -MSHIFT, -MSHIFT};
  const f32x4 zero4 = {0.f, 0.f, 0.f, 0.f};
  f32x4 acc[4][2];
#pragma unroll
  for (int i = 0; i < 4; ++i) { acc[i][0] = zero4; acc[i][1] = zero4; }
  float lsum[4] = {0.f, 0.f, 0.f, 0.f};

  // prologue: DMA tile 0 into buf 0
  gl_lds16(ksrc + (size_t)k0 * D, kdst);
  gl_lds16(vsrc + k0, vdst);
  __syncthreads();

#pragma unroll
  for (int t = 0; t < NT; ++t) {
    const int cur = t & 1;
    if (t + 1 < NT) {  // DMA tile t+1 into spare buffer
      const int kb = k0 + (t + 1) * 64;
      gl_lds16(ksrc + (size_t)kb * D, kdst + (cur ^ 1) * 2048);
      gl_lds16(vsrc + kb, vdst + (cur ^ 1) * 2048);
    }
    __builtin_amdgcn_sched_barrier(0);  // DMAs issue before compute

    // ---- LDS fragments of tile t ----
    bf16x8 kf[4];
#pragma unroll
    for (int t4 = 0; t4 < 4; ++t4) {
      const int row = 16 * t4 + a;
      kf[t4] = *reinterpret_cast<const bf16x8*>(
          &Ks[cur][row * 32 + ((g ^ ((a >> 1) & 3)) << 3)]);
    }
    bf16x4 v0[4], v1[4];
#pragma unroll
    for (int tt = 0; tt < 4; ++tt) {
      const int pb = ((tt << 1) + (g >> 1)) ^ (a & 7);
      const int off = pb * 8 + (g & 1) * 4;
      v0[tt] = *reinterpret_cast<const bf16x4*>(&Vs[cur][a * 64 + off]);
      v1[tt] = *reinterpret_cast<const bf16x4*>(&Vs[cur][(16 + a) * 64 + off]);
    }
    const bf16x8 va00 = __builtin_shufflevector(v0[0], v0[1], 0, 1, 2, 3, 4, 5, 6, 7);
    const bf16x8 va01 = __builtin_shufflevector(v0[2], v0[3], 0, 1, 2, 3, 4, 5, 6, 7);
    const bf16x8 va10 = __builtin_shufflevector(v1[0], v1[1], 0, 1, 2, 3, 4, 5, 6, 7);
    const bf16x8 va11 = __builtin_shufflevector(v1[2], v1[3], 0, 1, 2, 3, 4, 5, 6, 7);

    // ---- 4 q-tiles: S -> exp2 -> pack -> PV (independent chains) ----
#pragma unroll
    for (int i = 0; i < 4; ++i) {
      f32x4 s0 = __builtin_amdgcn_mfma_f32_16x16x32_bf16(kf[0], qf[i], minit, 0, 0, 0);
      f32x4 s1 = __builtin_amdgcn_mfma_f32_16x16x32_bf16(kf[1], qf[i], minit, 0, 0, 0);
      f32x4 s2 = __builtin_amdgcn_mfma_f32_16x16x32_bf16(kf[2], qf[i], minit, 0, 0, 0);
      f32x4 s3 = __builtin_amdgcn_mfma_f32_16x16x32_bf16(kf[3], qf[i], minit, 0, 0, 0);
      float p[16];
#pragma unroll
      for (int r = 0; r < 4; ++r) {
        p[r]      = __builtin_amdgcn_exp2f(s0[r]);
        p[4 + r]  = __builtin_amdgcn_exp2f(s1[r]);
        p[8 + r]  = __builtin_amdgcn_exp2f(s2[r]);
        p[12 + r] = __builtin_amdgcn_exp2f(s3[r]);
      }
      float ps = 0.f;
#pragma unroll
      for (int t4 = 0; t4 < 4; ++t4) {
        float sa = 0.f;
#pragma unroll
        for (int r = 0; r < 4; ++r) sa += p[4 * t4 + r];
        ps += sa;
      }
      lsum[i] += ps;
      const bf16x8 pf0 = {(__bf16)p[0], (__bf16)p[1], (__bf16)p[2], (__bf16)p[3],
                          (__bf16)p[4], (__bf16)p[5], (__bf16)p[6], (__bf16)p[7]};
      const bf16x8 pf1 = {(__bf16)p[8], (__bf16)p[9], (__bf16)p[10], (__bf16)p[11],
                          (__bf16)p[12], (__bf16)p[13], (__bf16)p[14], (__bf16)p[15]};
      acc[i][0] = __builtin_amdgcn_mfma_f32_16x16x32_bf16(va00, pf0, acc[i][0], 0, 0, 0);
      acc[i][1] = __builtin_amdgcn_mfma_f32_16x16x32_bf16(va10, pf0, acc[i][1], 0, 0, 0);
      acc[i][0] = __builtin_amdgcn_mfma_f32_16x16x32_bf16(va01, pf1, acc[i][0], 0, 0, 0);
      acc[i][1] = __builtin_amdgcn_mfma_f32_16x16x32_bf16(va11, pf1, acc[i][1], 0, 0, 0);
    }

    __syncthreads();  // DMA t+1 had the whole 4-q-tile compute phase in flight
  }

  // ---- epilogue: reduce l across g-groups, float4 partial stores ----
#pragma unroll
  for (int i = 0; i < 4; ++i) {
    float l = lsum[i];
    l += __shfl_xor(l, 16, 64);
    l += __shfl_xor(l, 32, 64);
    float* ob = OP + (size_t)(sp * N + qr0 + 16 * i + a) * D;
    *reinterpret_cast<f32x4*>(ob + 4 * g) = acc[i][0];
    *reinterpret_cast<f32x4*>(ob + 16 + 4 * g) = acc[i][1];
    if (g == 0) lP[sp * N + qr0 + 16 * i + a] = l;
  }
}

// ---------------- combine splits (fixed max -> plain sum), vectorized ----------------
template <int NS>
__global__ __launch_bounds__(256) void combine_kernel(
    const float* __restrict__ lP, const float* __restrict__ OP,
    float* __restrict__ out) {
  const int idx4 = blockIdx.x * 256 + threadIdx.x;  // float4 index
  if (idx4 >= (N * D) / 4) return;
  const int q = idx4 >> 3;
  float L = 0.f;
  f32x4 o = {0.f, 0.f, 0.f, 0.f};
#pragma unroll
  for (int s = 0; s < NS; ++s) {
    L += lP[s * N + q];
    o += *reinterpret_cast<const f32x4*>(OP + (size_t)s * N * D + (size_t)idx4 * 4);
  }
  const float inv = 1.0f / L;
  *reinterpret_cast<f32x4*>(out + (size_t)idx4 * 4) = o * inv;
}

extern "C" void kernel_launch(void* const* d_in, const int* in_sizes, int n_in,
                              void* d_out, int out_size, void* d_ws, size_t ws_size,
                              hipStream_t stream) {
  const float* Q = (const float*)d_in[0];
  const float* K = (const float*)d_in[1];
  const float* V = (const float*)d_in[2];
  float* out = (float*)d_out;

  const size_t base = (size_t)3 * N * D * sizeof(u16);
  const size_t per_split = (size_t)N * sizeof(float) + (size_t)N * D * sizeof(float);
  int ns = 16;
  while (ns > 4 && base + (size_t)ns * per_split > ws_size) ns >>= 1;

  u16* Qb = (u16*)d_ws;
  u16* Kb = Qb + N * D;
  u16* Vt = Kb + N * D;  // [D][N]
  float* lP = (float*)(Vt + N * D);
  float* OP = lP + ns * N;

  prep_kernel<<<256 + N / 64, 256, 0, stream>>>(Q, K, V, Qb, Kb, Vt);
  switch (ns) {
    case 16:
      flash_kernel<16><<<32 * 16, 256, 0, stream>>>(Qb, Kb, Vt, lP, OP);
      combine_kernel<16><<<(N * D) / 1024, 256, 0, stream>>>(lP, OP, out);
      break;
    case 8:
      flash_kernel<8><<<32 * 8, 256, 0, stream>>>(Qb, Kb, Vt, lP, OP);
      combine_kernel<8><<<(N * D) / 1024, 256, 0, stream>>>(lP, OP, out);
      break;
    default:
      flash_kernel<4><<<32 * 4, 256, 0, stream>>>(Qb, Kb, Vt, lP, OP);
      combine_kernel<4><<<(N * D) / 1024, 256, 0, stream>>>(lP, OP, out);
      break;
  }
}